// Round 5
// baseline (206.173 us; speedup 1.0000x reference)
//
#include <hip/hip_runtime.h>
#include <hip/hip_bf16.h>

#define B_  16
#define C_  256
#define H_  48
#define W_  64
#define ND  21           // displacements per axis
#define HW  (H_ * W_)
#define CHW (C_ * H_ * W_)

typedef __attribute__((ext_vector_type(8))) short bf16x8;
typedef __attribute__((ext_vector_type(4))) float f32x4;

__device__ __forceinline__ unsigned int bf16rtne(float f) {
  unsigned int u = __builtin_bit_cast(unsigned int, f);
  return (u + 0x7fffu + ((u >> 16) & 1u)) >> 16;
}

// ---------------------------------------------------------------------------
// Kernel 1 v2 (unchanged from R4): fp32 NCHW -> bf16 FRAGMENT-MAJOR, 2
// channel-half blocks per (input,b,y) row. grid = 4*B*H = 3072.
//   granule G = ks*256 + t16*64 + quad*16 + l15  (16B granules)
//   content  = bf16 src[x = t16*16+l15][k = ks*32+quad*8 .. +8)
// ---------------------------------------------------------------------------
__global__ __launch_bounds__(256, 8) void transpose_cvt(
    const float* __restrict__ in1, const float* __restrict__ in2,
    unsigned short* __restrict__ o1, unsigned short* __restrict__ o2) {
  __shared__ unsigned short T[128 * 66];   // [cl][x], stride 66 (odd word stride)

  int bid = blockIdx.x;
  int ch  = bid & 1;                       // channel half: c in [ch*128, ch*128+128)
  int blk = bid >> 1;
  const float* in = in1;
  unsigned short* op = o1;
  if (blk >= B_ * H_) { blk -= B_ * H_; in = in2; op = o2; }
  int y = blk % H_;
  int b = blk / H_;
  int t = threadIdx.x;

  // ---- phase 1: global fp32 -> bf16 -> LDS[cl][x] ----
  int u  = t & 15;          // x-quad: x = 4u..4u+3
  int cb = t >> 4;          // local c base 0..15, cl = cb + 16r
  const float* src = in + (long)b * CHW + (long)(ch * 128) * HW + y * W_ + u * 4;
#pragma unroll
  for (int r = 0; r < 8; r++) {
    int cl = cb + 16 * r;
    float4 v = *(const float4*)(src + (long)cl * HW);
    unsigned int p0 = bf16rtne(v.x) | (bf16rtne(v.y) << 16);
    unsigned int p1 = bf16rtne(v.z) | (bf16rtne(v.w) << 16);
    unsigned int* Tw = (unsigned int*)(T + cl * 66 + u * 4);
    Tw[0] = p0;
    Tw[1] = p1;
  }
  __syncthreads();

  // ---- phase 2: LDS gather -> fragment-major 16B stores ----
  int x   = t >> 2;         // pixel 0..63
  int cq  = t & 3;
  int t16 = x >> 4, xl = x & 15;
  unsigned short* orow = op + (long)(b * H_ + y) * (W_ * C_);
#pragma unroll
  for (int g = 0; g < 4; g++) {
    int gg = (g + cq) & 3;              // bank-spread rotation
    int kgl = cq * 4 + gg;              // local k-granule 0..15
    int c0 = kgl * 8;                   // first local channel of this granule
    unsigned int wv[4];
#pragma unroll
    for (int k2 = 0; k2 < 4; k2++) {
      unsigned int lo = T[(c0 + 2 * k2) * 66 + x];
      unsigned int hi = T[(c0 + 2 * k2 + 1) * 66 + x];
      wv[k2] = lo | (hi << 16);
    }
    int kg = ch * 16 + kgl;             // global k-granule 0..31
    int ks = kg >> 2, qd = kg & 3;
    int G = ks * 256 + t16 * 64 + qd * 16 + xl;
    *(uint4*)(orow + (long)G * 8) = *(uint4*)wv;
  }
}

// ---------------------------------------------------------------------------
// Kernel 2: correlation v10 — pin A in registers, vmcnt-free inner barrier.
// R4 diagnosis: VGPR_Count=80 < afrag(64)+acc(16)+B => the compiler was
// REMATERIALIZING afrag from global every dyi iteration and sinking B loads
// to just-before-use: ~32 serialized loads/iter = the latency wall that made
// v8's prefetch (and v9's depth-4) no-ops. v10:
//   - afrag passed through asm volatile("":"+v") after load: fragments
//     become opaque asm outputs -> cannot be rematerialized, must stay
//     resident (64+16+~64+misc ~= 165 <= 170 cap @ 3 waves/EU, no spill).
//   - in-loop barrier = s_waitcnt lgkmcnt(0) + raw s_barrier (NO vmcnt
//     drain): all cross-wave hazards are LDS-only; output store-acks and
//     in-flight B loads retire in the background (HK barrier technique).
//   - keeps: XCD swizzle (B L2-resident), bp[8][2] B buffer issued ahead
//     (ks0-3 before the store phase, distance-4 in-loop), double-buffered
//     output slab, coalesced stores.
// ---------------------------------------------------------------------------
__global__ __launch_bounds__(256, 3) void corr_kernel(
    const unsigned short* __restrict__ A2, const unsigned short* __restrict__ B2,
    float* __restrict__ out) {
  __shared__ float slab[2][ND * 65];        // [buf][dxi][x], pad 65

  int bid = blockIdx.x;
  int blk = (bid & 7) * 96 + (bid >> 3);    // XCD swizzle, bijective (768=8*96)
  int y    = blk % H_;
  int b    = blk / H_;
  int t    = threadIdx.x;
  int lane = t & 63;
  int w    = t >> 6;
  int l15  = lane & 15;
  int quad = lane >> 4;
  int mh   = w & 1;
  int nh   = w >> 1;

  // contiguous valid-dyi range: y2 = y + 2*d - 20 in [0,H)
  int dlo = (y < 20) ? ((21 - y) >> 1) : 0;
  int dhi = (67 - y) >> 1; if (dhi > 20) dhi = 20;

  // ---- A fragments: load once, then PIN in registers via asm anchor ----
  const unsigned short* rowA = A2 + (long)(b * H_ + y) * (W_ * C_);
  bf16x8 afrag[2][8];
#pragma unroll
  for (int mtl = 0; mtl < 2; mtl++) {
    int mtg = mh * 2 + mtl;
#pragma unroll
    for (int ks = 0; ks < 8; ks++)
      afrag[mtl][ks] = *(const bf16x8*)(rowA + ks * 2048 + mtg * 512 + lane * 8);
  }
  // anchor: each fragment becomes an opaque asm output -> no rematerialization
#pragma unroll
  for (int mtl = 0; mtl < 2; mtl++)
#pragma unroll
    for (int ks = 0; ks < 8; ks++)
      asm volatile("" : "+v"(afrag[mtl][ks]));

  // ---- per-lane slab-scatter offsets (dyi-invariant): dxi*65 + xx, or -1 ----
  int soff[2][2][4];
#pragma unroll
  for (int mtl = 0; mtl < 2; mtl++)
#pragma unroll
    for (int ntl = 0; ntl < 2; ntl++)
#pragma unroll
      for (int r = 0; r < 4; r++) {
        int xx = (mh * 2 + mtl) * 16 + quad * 4 + r;
        int xp = (nh * 2 + ntl) * 16 + l15;
        int dx = xp - xx;
        soff[mtl][ntl][r] =
            (dx >= -20 && dx <= 20 && !(dx & 1)) ? (((dx + 20) >> 1) * 65 + xx) : -1;
      }

  // tile-pair liveness (wave-uniform): |16*(ntg-mtg)| <= 35
  bool live[2][2];
#pragma unroll
  for (int mtl = 0; mtl < 2; mtl++)
#pragma unroll
    for (int ntl = 0; ntl < 2; ntl++) {
      int diff = (nh * 2 + ntl) - (mh * 2 + mtl);
      live[mtl][ntl] = (diff >= -2 && diff <= 2);
    }

  float* ob = out + (long)b * (ND * ND * HW) + y * W_;

  // ---- zero planes for out-of-range dyi (coalesced) ----
  for (int d = 0; d < dlo; d++) {
    float* od = ob + (long)d * (ND * HW);
    for (int i = t; i < ND * W_; i += 256) od[(i >> 6) * HW + (i & 63)] = 0.0f;
  }
  for (int d = dhi + 1; d < ND; d++) {
    float* od = ob + (long)d * (ND * HW);
    for (int i = t; i < ND * W_; i += 256) od[(i >> 6) * HW + (i & 63)] = 0.0f;
  }

  // ---- zero-init both slabs (contiguous) ----
  {
    float* s0 = &slab[0][0];
    for (int i = t; i < 2 * ND * 65; i += 256) s0[i] = 0.0f;
  }
  __syncthreads();   // prologue: full barrier once

  const unsigned short* browbase = B2 + (long)(b * H_) * (W_ * C_);
  int sp = 0;
  for (int d = dlo; d <= dhi; d++) {
    int y2 = y + 2 * d - 20;
    const unsigned short* rowB = browbase + (long)y2 * (W_ * C_);
    const unsigned short* rb0 = rowB + (nh * 2 + 0) * 512 + lane * 8;
    const unsigned short* rb1 = rowB + (nh * 2 + 1) * 512 + lane * 8;

    // ---- (0) issue B loads for ks 0..3; slab-store phase covers latency ----
    bf16x8 bp[8][2];
#pragma unroll
    for (int ks = 0; ks < 4; ks++) {
      bp[ks][0] = *(const bf16x8*)(rb0 + ks * 2048);
      bp[ks][1] = *(const bf16x8*)(rb1 + ks * 2048);
    }

    // ---- (1) store previous dyi's slab (coalesced 256B/wave) + rezero ----
    if (d > dlo) {
      float* odp = ob + (long)(d - 1) * (ND * HW);
      float* sl = slab[sp ^ 1];
      for (int i = t; i < ND * W_; i += 256) {
        int dxi = i >> 6, x = i & 63;
        odp[dxi * HW + x] = sl[dxi * 65 + x];
        sl[dxi * 65 + x] = 0.0f;
      }
    }

    // ---- (2) MFMA loop, in-loop prefetch at distance 4 ks ----
    f32x4 acc[2][2];
#pragma unroll
    for (int mtl = 0; mtl < 2; mtl++)
#pragma unroll
      for (int ntl = 0; ntl < 2; ntl++) acc[mtl][ntl] = (f32x4){0.f, 0.f, 0.f, 0.f};

#pragma unroll
    for (int ks = 0; ks < 8; ks++) {
      if (ks < 4) {
        bp[ks + 4][0] = *(const bf16x8*)(rb0 + (ks + 4) * 2048);
        bp[ks + 4][1] = *(const bf16x8*)(rb1 + (ks + 4) * 2048);
      }
#pragma unroll
      for (int mtl = 0; mtl < 2; mtl++) {
        if (live[mtl][0])
          acc[mtl][0] = __builtin_amdgcn_mfma_f32_16x16x32_bf16(afrag[mtl][ks], bp[ks][0],
                                                                acc[mtl][0], 0, 0, 0);
        if (live[mtl][1])
          acc[mtl][1] = __builtin_amdgcn_mfma_f32_16x16x32_bf16(afrag[mtl][ks], bp[ks][1],
                                                                acc[mtl][1], 0, 0, 0);
      }
    }

    // ---- (3) band-extract scatter into slab[sp] ----
#pragma unroll
    for (int mtl = 0; mtl < 2; mtl++)
#pragma unroll
      for (int ntl = 0; ntl < 2; ntl++)
#pragma unroll
        for (int r = 0; r < 4; r++) {
          int so = soff[mtl][ntl][r];
          if (so >= 0) slab[sp][so] = acc[mtl][ntl][r] * (1.0f / 256.0f);
        }

    // ---- (4) relaxed barrier: LDS drained, NO vmcnt drain ----
    //      (all cross-wave hazards are LDS; output stores never re-read;
    //       B loads are consumed by MFMA dataflow)
    asm volatile("s_waitcnt lgkmcnt(0)" ::: "memory");
    __builtin_amdgcn_s_barrier();
    __builtin_amdgcn_sched_barrier(0);
    sp ^= 1;
  }

  // ---- epilogue: store last dyi's slab ----
  {
    float* odp = ob + (long)dhi * (ND * HW);
    float* sl = slab[sp ^ 1];
    for (int i = t; i < ND * W_; i += 256) {
      int dxi = i >> 6, x = i & 63;
      odp[dxi * HW + x] = sl[dxi * 65 + x];
    }
  }
}

// ---------------------------------------------------------------------------
extern "C" void kernel_launch(void* const* d_in, const int* in_sizes, int n_in,
                              void* d_out, int out_size, void* d_ws, size_t ws_size,
                              hipStream_t stream) {
  (void)in_sizes; (void)n_in; (void)out_size; (void)ws_size;
  const float* in1 = (const float*)d_in[0];
  const float* in2 = (const float*)d_in[1];
  float* out = (float*)d_out;

  unsigned short* o1 = (unsigned short*)d_ws;                    // bf16 frag-major
  unsigned short* o2 = o1 + (size_t)B_ * H_ * W_ * C_;           // bf16 frag-major

  transpose_cvt<<<4 * B_ * H_, 256, 0, stream>>>(in1, in2, o1, o2);
  corr_kernel<<<B_ * H_, 256, 0, stream>>>(o1, o2, out);
}